// Round 1
// baseline (82329.529 us; speedup 1.0000x reference)
//
#include <hip/hip_runtime.h>
#include <math.h>
#include <cstddef>

#define BB    128
#define NSTOCH 128
#define DETER 1024
#define NEMB  512
#define OBSD  512
#define G3    3072

__device__ __forceinline__ float sigmoidf_(float x) { return 1.0f / (1.0f + expf(-x)); }

// ---------------------------------------------------------------------------
// zero two buffers (state init per level)
__global__ void zero2_k(float* a, int na, float* b, int nb) {
    int i = blockIdx.x * blockDim.x + threadIdx.x;
    int stride = gridDim.x * blockDim.x;
    for (int j = i; j < na; j += stride) a[j] = 0.0f;
    for (int j = i; j < nb; j += stride) b[j] = 0.0f;
}

// ---------------------------------------------------------------------------
// GRU step: det_out = GRU(h, det_in); also writes dets_seq[:, t, :]
// grid (DETER/32, BB/16), block 256.  Thread: d = bx*32 + tid%32, two b's.
__global__ __launch_bounds__(256)
void gru_step_k(const float* __restrict__ h,       // B x 512 (post-relu)
                const float* __restrict__ det_in,  // B x 1024
                float* __restrict__ det_out,       // B x 1024
                float* __restrict__ dets_seq,      // B x T x 1024
                const float* __restrict__ Wih,     // 512 x 3072
                const float* __restrict__ Whh,     // 1024 x 3072
                const float* __restrict__ bih,     // 3072
                const float* __restrict__ bhh,     // 3072
                int t, int T)
{
    __shared__ float xs[16][65];
    const int tid = threadIdx.x;
    const int dl = tid & 31;
    const int bl = tid >> 5;                  // 0..7
    const int d  = blockIdx.x * 32 + dl;
    const int b0 = blockIdx.y * 16;

    float ar0 = 0.f, az0 = 0.f, ain0 = 0.f, ahn0 = 0.f;
    float ar1 = 0.f, az1 = 0.f, ain1 = 0.f, ahn1 = 0.f;

    // phase 0: x = h (K=512), W = Wih -> r, z, in
    for (int kc = 0; kc < NEMB; kc += 64) {
        __syncthreads();
        for (int i = tid; i < 16 * 64; i += 256) {
            int r = i >> 6, c = i & 63;
            xs[r][c] = h[(size_t)(b0 + r) * NEMB + kc + c];
        }
        __syncthreads();
        #pragma unroll 16
        for (int kk = 0; kk < 64; ++kk) {
            const float* w = Wih + (size_t)(kc + kk) * G3 + d;
            float wr = w[0], wz = w[1024], wn = w[2048];
            float xa = xs[bl][kk], xb = xs[bl + 8][kk];
            ar0 += xa * wr; az0 += xa * wz; ain0 += xa * wn;
            ar1 += xb * wr; az1 += xb * wz; ain1 += xb * wn;
        }
    }
    // phase 1: x = det_in (K=1024), W = Whh -> r, z, hn
    for (int kc = 0; kc < DETER; kc += 64) {
        __syncthreads();
        for (int i = tid; i < 16 * 64; i += 256) {
            int r = i >> 6, c = i & 63;
            xs[r][c] = det_in[(size_t)(b0 + r) * DETER + kc + c];
        }
        __syncthreads();
        #pragma unroll 16
        for (int kk = 0; kk < 64; ++kk) {
            const float* w = Whh + (size_t)(kc + kk) * G3 + d;
            float wr = w[0], wz = w[1024], wn = w[2048];
            float xa = xs[bl][kk], xb = xs[bl + 8][kk];
            ar0 += xa * wr; az0 += xa * wz; ahn0 += xa * wn;
            ar1 += xb * wr; az1 += xb * wz; ahn1 += xb * wn;
        }
    }

    const float br  = bih[d] + bhh[d];
    const float bz  = bih[1024 + d] + bhh[1024 + d];
    const float bin = bih[2048 + d];
    const float bhn = bhh[2048 + d];

    {
        int b = b0 + bl;
        float dold = det_in[(size_t)b * DETER + d];
        float r = sigmoidf_(ar0 + br);
        float z = sigmoidf_(az0 + bz);
        float n = tanhf(ain0 + bin + r * (ahn0 + bhn));
        float dn = (1.0f - z) * n + z * dold;
        det_out[(size_t)b * DETER + d] = dn;
        dets_seq[((size_t)b * T + t) * DETER + d] = dn;
    }
    {
        int b = b0 + bl + 8;
        float dold = det_in[(size_t)b * DETER + d];
        float r = sigmoidf_(ar1 + br);
        float z = sigmoidf_(az1 + bz);
        float n = tanhf(ain1 + bin + r * (ahn1 + bhn));
        float dn = (1.0f - z) * n + z * dold;
        det_out[(size_t)b * DETER + d] = dn;
        dets_seq[((size_t)b * T + t) * DETER + d] = dn;
    }
}

// ---------------------------------------------------------------------------
// qh = relu([det_new, obs_t] @ Wq + bq)
// grid (NEMB/32, BB/16), block 256
__global__ __launch_bounds__(256)
void qh_k(const float* __restrict__ det,  // B x 1024
          const float* __restrict__ obs,  // B x T x 512
          const float* __restrict__ Wq,   // 1536 x 512
          const float* __restrict__ bq,   // 512
          float* __restrict__ qh,         // B x 512
          int t, int T)
{
    __shared__ float xs[16][65];
    const int tid = threadIdx.x;
    const int nl = tid & 31;
    const int bl = tid >> 5;
    const int n  = blockIdx.x * 32 + nl;
    const int b0 = blockIdx.y * 16;

    float a0 = 0.f, a1 = 0.f;

    // det part (rows 0..1023)
    for (int kc = 0; kc < DETER; kc += 64) {
        __syncthreads();
        for (int i = tid; i < 16 * 64; i += 256) {
            int r = i >> 6, c = i & 63;
            xs[r][c] = det[(size_t)(b0 + r) * DETER + kc + c];
        }
        __syncthreads();
        #pragma unroll 16
        for (int kk = 0; kk < 64; ++kk) {
            float w = Wq[(size_t)(kc + kk) * NEMB + n];
            a0 += xs[bl][kk] * w;
            a1 += xs[bl + 8][kk] * w;
        }
    }
    // obs part (rows 1024..1535)
    for (int kc = 0; kc < OBSD; kc += 64) {
        __syncthreads();
        for (int i = tid; i < 16 * 64; i += 256) {
            int r = i >> 6, c = i & 63;
            xs[r][c] = obs[((size_t)(b0 + r) * T + t) * OBSD + kc + c];
        }
        __syncthreads();
        #pragma unroll 16
        for (int kk = 0; kk < 64; ++kk) {
            float w = Wq[(size_t)(DETER + kc + kk) * NEMB + n];
            a0 += xs[bl][kk] * w;
            a1 += xs[bl + 8][kk] * w;
        }
    }

    float bias = bq[n];
    qh[(size_t)(b0 + bl) * NEMB + n]     = fmaxf(a0 + bias, 0.0f);
    qh[(size_t)(b0 + bl + 8) * NEMB + n] = fmaxf(a1 + bias, 0.0f);
}

// ---------------------------------------------------------------------------
// sample = qh @ Wqm + bqm
// grid (NSTOCH/32, BB/16), block 256
__global__ __launch_bounds__(256)
void sample_k(const float* __restrict__ qh,   // B x 512
              const float* __restrict__ Wqm,  // 512 x 128
              const float* __restrict__ bqm,  // 128
              float* __restrict__ sample)     // B x 128
{
    __shared__ float xs[16][65];
    const int tid = threadIdx.x;
    const int nl = tid & 31;
    const int bl = tid >> 5;
    const int n  = blockIdx.x * 32 + nl;
    const int b0 = blockIdx.y * 16;

    float a0 = 0.f, a1 = 0.f;
    for (int kc = 0; kc < NEMB; kc += 64) {
        __syncthreads();
        for (int i = tid; i < 16 * 64; i += 256) {
            int r = i >> 6, c = i & 63;
            xs[r][c] = qh[(size_t)(b0 + r) * NEMB + kc + c];
        }
        __syncthreads();
        #pragma unroll 16
        for (int kk = 0; kk < 64; ++kk) {
            float w = Wqm[(size_t)(kc + kk) * NSTOCH + n];
            a0 += xs[bl][kk] * w;
            a1 += xs[bl + 8][kk] * w;
        }
    }
    float bias = bqm[n];
    sample[(size_t)(b0 + bl) * NSTOCH + n]     = a0 + bias;
    sample[(size_t)(b0 + bl + 8) * NSTOCH + n] = a1 + bias;
}

// ---------------------------------------------------------------------------
// h = relu([sample, ctx_t] @ Wp + bp); ctx_t = ctx[b, tn % Tc, :] or zeros
// grid (NEMB/32, BB/16), block 256
__global__ __launch_bounds__(256)
void h_k(const float* __restrict__ sample,  // B x 128
         const float* __restrict__ ctx,     // B x Tc x 1024 (may be null)
         int Tc, int tn,
         const float* __restrict__ Wp,      // 1152 x 512
         const float* __restrict__ bp,      // 512
         float* __restrict__ hout,          // B x 512
         int has_ctx)
{
    __shared__ float xs[16][65];
    const int tid = threadIdx.x;
    const int nl = tid & 31;
    const int bl = tid >> 5;
    const int n  = blockIdx.x * 32 + nl;
    const int b0 = blockIdx.y * 16;

    float a0 = 0.f, a1 = 0.f;

    // sample part (rows 0..127)
    for (int kc = 0; kc < NSTOCH; kc += 64) {
        __syncthreads();
        for (int i = tid; i < 16 * 64; i += 256) {
            int r = i >> 6, c = i & 63;
            xs[r][c] = sample[(size_t)(b0 + r) * NSTOCH + kc + c];
        }
        __syncthreads();
        #pragma unroll 16
        for (int kk = 0; kk < 64; ++kk) {
            float w = Wp[(size_t)(kc + kk) * NEMB + n];
            a0 += xs[bl][kk] * w;
            a1 += xs[bl + 8][kk] * w;
        }
    }
    // ctx part (rows 128..1151)
    if (has_ctx) {
        int tc = tn % Tc;
        for (int kc = 0; kc < DETER; kc += 64) {
            __syncthreads();
            for (int i = tid; i < 16 * 64; i += 256) {
                int r = i >> 6, c = i & 63;
                xs[r][c] = ctx[((size_t)(b0 + r) * Tc + tc) * DETER + kc + c];
            }
            __syncthreads();
            #pragma unroll 16
            for (int kk = 0; kk < 64; ++kk) {
                float w = Wp[(size_t)(NSTOCH + kc + kk) * NEMB + n];
                a0 += xs[bl][kk] * w;
                a1 += xs[bl + 8][kk] * w;
            }
        }
    }

    float bias = bp[n];
    hout[(size_t)(b0 + bl) * NEMB + n]     = fmaxf(a0 + bias, 0.0f);
    hout[(size_t)(b0 + bl + 8) * NEMB + n] = fmaxf(a1 + bias, 0.0f);
}

// ---------------------------------------------------------------------------
extern "C" void kernel_launch(void* const* d_in, const int* in_sizes, int n_in,
                              void* d_out, int out_size, void* d_ws, size_t ws_size,
                              hipStream_t stream)
{
    const float* obs0 = (const float*)d_in[0];
    const float* obs1 = (const float*)d_in[1];
    const float* obs2 = (const float*)d_in[2];
    const float* Wp   = (const float*)d_in[3];
    const float* bp   = (const float*)d_in[4];
    const float* Wih  = (const float*)d_in[5];
    const float* Whh  = (const float*)d_in[6];
    const float* bih  = (const float*)d_in[7];
    const float* bhh  = (const float*)d_in[8];
    const float* Wq   = (const float*)d_in[9];
    const float* bq   = (const float*)d_in[10];
    const float* Wqm  = (const float*)d_in[11];
    const float* bqm  = (const float*)d_in[12];

    float* ws = (float*)d_ws;
    float* det_a  = ws;  ws += (size_t)BB * DETER;
    float* det_b  = ws;  ws += (size_t)BB * DETER;
    float* sample = ws;  ws += (size_t)BB * NSTOCH;
    float* hbuf   = ws;  ws += (size_t)BB * NEMB;
    float* qhbuf  = ws;  ws += (size_t)BB * NEMB;
    float* dets2  = ws;  ws += (size_t)BB * 16 * DETER;
    float* dets1  = ws;  ws += (size_t)BB * 64 * DETER;

    const float* obsv[3] = {obs0, obs1, obs2};
    const int Tv[3] = {256, 64, 16};

    for (int level = 2; level >= 0; --level) {
        const int T = Tv[level];
        const float* o = obsv[level];
        float* dseq = (level == 0) ? (float*)d_out : (level == 1 ? dets1 : dets2);
        const float* ctx = (level == 2) ? nullptr : (level == 1 ? dets2 : dets1);
        const int Tc = (level == 1) ? 16 : 64;  // prev (coarser) level T; unused for level 2
        const int has_ctx = (ctx != nullptr) ? 1 : 0;

        const float* Wp_l  = Wp  + (size_t)level * 1152 * 512;
        const float* bp_l  = bp  + (size_t)level * 512;
        const float* Wih_l = Wih + (size_t)level * 512 * 3072;
        const float* Whh_l = Whh + (size_t)level * 1024 * 3072;
        const float* bih_l = bih + (size_t)level * 3072;
        const float* bhh_l = bhh + (size_t)level * 3072;
        const float* Wq_l  = Wq  + (size_t)level * 1536 * 512;
        const float* bq_l  = bq  + (size_t)level * 512;
        const float* Wqm_l = Wqm + (size_t)level * 512 * 128;
        const float* bqm_l = bqm + (size_t)level * 128;

        zero2_k<<<dim3(64), dim3(256), 0, stream>>>(det_a, BB * DETER, sample, BB * NSTOCH);
        h_k<<<dim3(16, 8), dim3(256), 0, stream>>>(sample, ctx, Tc, 0, Wp_l, bp_l, hbuf, has_ctx);

        for (int t = 0; t < T; ++t) {
            float* din  = (t & 1) ? det_b : det_a;
            float* dnew = (t & 1) ? det_a : det_b;
            gru_step_k<<<dim3(32, 8), dim3(256), 0, stream>>>(hbuf, din, dnew, dseq,
                                                              Wih_l, Whh_l, bih_l, bhh_l, t, T);
            qh_k<<<dim3(16, 8), dim3(256), 0, stream>>>(dnew, o, Wq_l, bq_l, qhbuf, t, T);
            sample_k<<<dim3(4, 8), dim3(256), 0, stream>>>(qhbuf, Wqm_l, bqm_l, sample);
            if (t + 1 < T) {
                h_k<<<dim3(16, 8), dim3(256), 0, stream>>>(sample, ctx, Tc, t + 1,
                                                           Wp_l, bp_l, hbuf, has_ctx);
            }
        }
    }
}

// Round 2
// 78774.738 us; speedup vs baseline: 1.0451x; 1.0451x over previous
//
#include <hip/hip_runtime.h>
#include <math.h>
#include <cstddef>

#define G3 3072

__device__ __forceinline__ float sigmoidf_(float x){ return 1.0f/(1.0f+expf(-x)); }

// ---------------------------------------------------------------------------
__global__ __launch_bounds__(256)
void zero_k(float* p, int n){
    int i = blockIdx.x*blockDim.x + threadIdx.x;
    for (int j = i; j < n; j += gridDim.x*blockDim.x) p[j] = 0.f;
}

// ---------------------------------------------------------------------------
// C[M x N] = A[M x K] @ B[K x N] (+bias). grid (N/64, M/16), block 256.
// Thread: 2 cols (float2 W loads) x 2 rows. Used for per-level Wqs precompute.
__global__ __launch_bounds__(256)
void gemm_k(const float* __restrict__ A, long lda,
            const float* __restrict__ Bm, long ldb,
            const float* __restrict__ bias,
            float* __restrict__ C, long ldc, int K)
{
    __shared__ float xs[16][64];
    const int tid = threadIdx.x;
    const int nl = tid & 31, bl = tid >> 5;
    const int n  = blockIdx.x*64 + nl*2;
    const int m0 = blockIdx.y*16;
    float a0x=0.f,a0y=0.f,a1x=0.f,a1y=0.f;
    for (int kc = 0; kc < K; kc += 64) {
        __syncthreads();
        { int r = tid >> 4, c = (tid & 15)*4;
          *(float4*)&xs[r][c] = *(const float4*)&A[(size_t)(m0+r)*lda + kc + c]; }
        __syncthreads();
        #pragma unroll 8
        for (int kk = 0; kk < 64; ++kk) {
            const float2 w = *(const float2*)&Bm[(size_t)(kc+kk)*ldb + n];
            const float xa = xs[bl][kk], xb = xs[bl+8][kk];
            a0x += xa*w.x; a0y += xa*w.y;
            a1x += xb*w.x; a1y += xb*w.y;
        }
    }
    float bx=0.f, by=0.f;
    if (bias){ bx = bias[n]; by = bias[n+1]; }
    float* c0 = &C[(size_t)(m0+bl)*ldc + n];
    float* c1 = &C[(size_t)(m0+bl+8)*ldc + n];
    c0[0]=a0x+bx; c0[1]=a0y+by; c1[0]=a1x+bx; c1[1]=a1y+by;
}

// ---------------------------------------------------------------------------
// bps = bp + bqm @ Wp_s   (Wp_s = first 128 rows of Wp_l). 1 block x 512.
__global__ __launch_bounds__(512)
void bps_k(const float* __restrict__ bqm, const float* __restrict__ Wps,
           const float* __restrict__ bp, float* __restrict__ bps)
{
    const int n = threadIdx.x;
    float a = 0.f;
    #pragma unroll 8
    for (int k = 0; k < 128; ++k) a += bqm[k]*Wps[(size_t)k*512 + n];
    bps[n] = a + bp[n];
}

// ---------------------------------------------------------------------------
// h = relu( (qh? qh@Wqs : 0) + (ctx? ctx_t@Wpc : 0) + bias )
// grid (16,16), block 256: n = bx*32 + (tid&31), b = by*8 + (tid>>5)
__global__ __launch_bounds__(256)
void h_k(const float* __restrict__ qh,            // B x 512, or null (t==0)
         const float* __restrict__ Wqs,           // 512 x 512
         const float* __restrict__ ctx, long ld_ctx, // pre-offset to tc; or null
         const float* __restrict__ Wpc,           // 1024 x 512 (Wp rows 128..1151)
         const float* __restrict__ bias,          // bps (t>0) or bp (t==0)
         float* __restrict__ hout)                // B x 512
{
    __shared__ float xs[8][128];
    const int tid = threadIdx.x;
    const int nl = tid & 31, bl = tid >> 5;
    const int n  = blockIdx.x*32 + nl;
    const int b0 = blockIdx.y*8;
    float a = 0.f;
    if (qh) {
        for (int kc = 0; kc < 512; kc += 128) {
            __syncthreads();
            *(float4*)&xs[bl][nl*4] = *(const float4*)&qh[(size_t)(b0+bl)*512 + kc + nl*4];
            __syncthreads();
            #pragma unroll 16
            for (int kk = 0; kk < 128; ++kk)
                a += xs[bl][kk] * Wqs[(size_t)(kc+kk)*512 + n];
        }
    }
    if (ctx) {
        for (int kc = 0; kc < 1024; kc += 128) {
            __syncthreads();
            *(float4*)&xs[bl][nl*4] = *(const float4*)&ctx[(size_t)(b0+bl)*ld_ctx + kc + nl*4];
            __syncthreads();
            #pragma unroll 16
            for (int kk = 0; kk < 128; ++kk)
                a += xs[bl][kk] * Wpc[(size_t)(kc+kk)*512 + n];
        }
    }
    hout[(size_t)(b0+bl)*512 + n] = fmaxf(a + bias[n], 0.f);
}

// ---------------------------------------------------------------------------
// GRU step, fused GEMM+pointwise. grid (16,16), block 256.
// Thread: d = bx*64 + (tid&31)*2 (2 cols, float2 W loads), b = by*8 + (tid>>5).
__global__ __launch_bounds__(256)
void gru_k(const float* __restrict__ h,              // B x 512
           const float* __restrict__ det_in, long ld_det,
           float* __restrict__ det_out, long ld_out, // = dets_seq + t*1024
           const float* __restrict__ Wih, const float* __restrict__ Whh,
           const float* __restrict__ bih, const float* __restrict__ bhh)
{
    __shared__ float xs[8][128];
    const int tid = threadIdx.x;
    const int dl = tid & 31, bl = tid >> 5;
    const int d  = blockIdx.x*64 + dl*2;
    const int b0 = blockIdx.y*8;
    float arx=0.f,ary=0.f, azx=0.f,azy=0.f, aix=0.f,aiy=0.f, ahx=0.f,ahy=0.f;

    // gi contributions: h @ Wih  (K = 512)
    for (int kc = 0; kc < 512; kc += 128) {
        __syncthreads();
        *(float4*)&xs[bl][dl*4] = *(const float4*)&h[(size_t)(b0+bl)*512 + kc + dl*4];
        __syncthreads();
        #pragma unroll 8
        for (int kk = 0; kk < 128; ++kk) {
            const float* w = Wih + (size_t)(kc+kk)*G3 + d;
            const float2 wr = *(const float2*)w;
            const float2 wz = *(const float2*)(w + 1024);
            const float2 wn = *(const float2*)(w + 2048);
            const float xa = xs[bl][kk];
            arx += xa*wr.x; ary += xa*wr.y;
            azx += xa*wz.x; azy += xa*wz.y;
            aix += xa*wn.x; aiy += xa*wn.y;
        }
    }
    // gh contributions: det_in @ Whh  (K = 1024)
    for (int kc = 0; kc < 1024; kc += 128) {
        __syncthreads();
        *(float4*)&xs[bl][dl*4] = *(const float4*)&det_in[(size_t)(b0+bl)*ld_det + kc + dl*4];
        __syncthreads();
        #pragma unroll 8
        for (int kk = 0; kk < 128; ++kk) {
            const float* w = Whh + (size_t)(kc+kk)*G3 + d;
            const float2 wr = *(const float2*)w;
            const float2 wz = *(const float2*)(w + 1024);
            const float2 wn = *(const float2*)(w + 2048);
            const float xa = xs[bl][kk];
            arx += xa*wr.x; ary += xa*wr.y;
            azx += xa*wz.x; azy += xa*wz.y;
            ahx += xa*wn.x; ahy += xa*wn.y;
        }
    }

    const float2 brI = *(const float2*)&bih[d];
    const float2 brH = *(const float2*)&bhh[d];
    const float2 bzI = *(const float2*)&bih[1024+d];
    const float2 bzH = *(const float2*)&bhh[1024+d];
    const float2 bnI = *(const float2*)&bih[2048+d];
    const float2 bnH = *(const float2*)&bhh[2048+d];
    const int b = b0 + bl;
    const float2 dold = *(const float2*)&det_in[(size_t)b*ld_det + d];

    const float rx = sigmoidf_(arx + brI.x + brH.x);
    const float ry = sigmoidf_(ary + brI.y + brH.y);
    const float zx = sigmoidf_(azx + bzI.x + bzH.x);
    const float zy = sigmoidf_(azy + bzI.y + bzH.y);
    const float nx = tanhf(aix + bnI.x + rx*(ahx + bnH.x));
    const float ny = tanhf(aiy + bnI.y + ry*(ahy + bnH.y));
    float2 dn;
    dn.x = (1.f - zx)*nx + zx*dold.x;
    dn.y = (1.f - zy)*ny + zy*dold.y;
    *(float2*)&det_out[(size_t)b*ld_out + d] = dn;
}

// ---------------------------------------------------------------------------
// qh = relu(det_t @ Wq[0:1024] + obs_t @ Wq[1024:1536] + bq)
// grid (16,16), block 256
__global__ __launch_bounds__(256)
void qh_k(const float* __restrict__ det, long ld_det,   // pre-offset to step t
          const float* __restrict__ obs, long ld_obs,   // pre-offset to step t
          const float* __restrict__ Wq,                  // 1536 x 512
          const float* __restrict__ bq,
          float* __restrict__ qh)                        // B x 512
{
    __shared__ float xs[8][128];
    const int tid = threadIdx.x;
    const int nl = tid & 31, bl = tid >> 5;
    const int n  = blockIdx.x*32 + nl;
    const int b0 = blockIdx.y*8;
    float a = 0.f;
    for (int kc = 0; kc < 1024; kc += 128) {
        __syncthreads();
        *(float4*)&xs[bl][nl*4] = *(const float4*)&det[(size_t)(b0+bl)*ld_det + kc + nl*4];
        __syncthreads();
        #pragma unroll 16
        for (int kk = 0; kk < 128; ++kk)
            a += xs[bl][kk] * Wq[(size_t)(kc+kk)*512 + n];
    }
    for (int kc = 0; kc < 512; kc += 128) {
        __syncthreads();
        *(float4*)&xs[bl][nl*4] = *(const float4*)&obs[(size_t)(b0+bl)*ld_obs + kc + nl*4];
        __syncthreads();
        #pragma unroll 16
        for (int kk = 0; kk < 128; ++kk)
            a += xs[bl][kk] * Wq[(size_t)(1024+kc+kk)*512 + n];
    }
    qh[(size_t)(b0+bl)*512 + n] = fmaxf(a + bq[n], 0.f);
}

// ---------------------------------------------------------------------------
extern "C" void kernel_launch(void* const* d_in, const int* in_sizes, int n_in,
                              void* d_out, int out_size, void* d_ws, size_t ws_size,
                              hipStream_t stream)
{
    const float* obs0 = (const float*)d_in[0];
    const float* obs1 = (const float*)d_in[1];
    const float* obs2 = (const float*)d_in[2];
    const float* Wp   = (const float*)d_in[3];
    const float* bp   = (const float*)d_in[4];
    const float* Wih  = (const float*)d_in[5];
    const float* Whh  = (const float*)d_in[6];
    const float* bih  = (const float*)d_in[7];
    const float* bhh  = (const float*)d_in[8];
    const float* Wq   = (const float*)d_in[9];
    const float* bq   = (const float*)d_in[10];
    const float* Wqm  = (const float*)d_in[11];
    const float* bqm  = (const float*)d_in[12];

    float* ws = (float*)d_ws;
    float* det0 = ws;  ws += (size_t)128*1024;      // zero initial state
    float* hbuf = ws;  ws += (size_t)128*512;
    float* qhb  = ws;  ws += (size_t)128*512;
    float* WqsA = ws;  ws += (size_t)3*512*512;     // folded Wqm@Wp_s per level
    float* bpsA = ws;  ws += (size_t)3*512;         // folded bias per level
    float* dets2= ws;  ws += (size_t)128*16*1024;
    float* dets1= ws;  ws += (size_t)128*64*1024;

    zero_k<<<dim3(128), dim3(256), 0, stream>>>(det0, 128*1024);

    // Per-level precompute: Wqs = Wqm @ Wp_s ; bps = bp + bqm @ Wp_s
    for (int l = 0; l < 3; ++l) {
        const float* Wp_l = Wp + (size_t)l*1152*512;
        gemm_k<<<dim3(8,32), dim3(256), 0, stream>>>(
            Wqm + (size_t)l*512*128, 128, Wp_l, 512, nullptr,
            WqsA + (size_t)l*512*512, 512, 128);
        bps_k<<<dim3(1), dim3(512), 0, stream>>>(
            bqm + (size_t)l*128, Wp_l, bp + (size_t)l*512, bpsA + (size_t)l*512);
    }

    const float* obsv[3] = {obs0, obs1, obs2};
    const int Tv[3] = {256, 64, 16};

    for (int level = 2; level >= 0; --level) {
        const int T = Tv[level];
        const float* o = obsv[level];
        float* dseq = (level == 0) ? (float*)d_out : (level == 1 ? dets1 : dets2);
        const float* ctxd = (level == 2) ? nullptr : (level == 1 ? dets2 : dets1);
        const int Tc = (level == 1) ? 16 : 64;

        const float* Wp_l  = Wp  + (size_t)level*1152*512;
        const float* Wpc_l = Wp_l + (size_t)128*512;     // ctx rows of Wp
        const float* bp_l  = bp  + (size_t)level*512;
        const float* Wih_l = Wih + (size_t)level*512*3072;
        const float* Whh_l = Whh + (size_t)level*1024*3072;
        const float* bih_l = bih + (size_t)level*3072;
        const float* bhh_l = bhh + (size_t)level*3072;
        const float* Wq_l  = Wq  + (size_t)level*1536*512;
        const float* bq_l  = bq  + (size_t)level*512;
        const float* Wqs_l = WqsA + (size_t)level*512*512;
        const float* bps_l = bpsA + (size_t)level*512;

        for (int t = 0; t < T; ++t) {
            const float* ctxp = ctxd ? (ctxd + (size_t)(t % Tc)*1024) : nullptr;
            h_k<<<dim3(16,16), dim3(256), 0, stream>>>(
                t ? qhb : nullptr, Wqs_l, ctxp, (long)Tc*1024, Wpc_l,
                t ? bps_l : bp_l, hbuf);
            gru_k<<<dim3(16,16), dim3(256), 0, stream>>>(
                hbuf,
                t ? dseq + (size_t)(t-1)*1024 : det0, t ? (long)T*1024 : 1024L,
                dseq + (size_t)t*1024, (long)T*1024,
                Wih_l, Whh_l, bih_l, bhh_l);
            if (t + 1 < T)
                qh_k<<<dim3(16,16), dim3(256), 0, stream>>>(
                    dseq + (size_t)t*1024, (long)T*1024,
                    o + (size_t)t*512, (long)T*512,
                    Wq_l, bq_l, qhb);
        }
    }
}